// Round 1
// baseline (24071.889 us; speedup 1.0000x reference)
//
#include <hip/hip_runtime.h>
#include <hip/hip_bf16.h>
#include <cstddef>

#define S_LEN 512
#define BATCH 64
#define HID 256
#define G3 768
#define SB (S_LEN*BATCH)
#define D2 512

typedef unsigned short u16;

__device__ __forceinline__ float bf2f(u16 u) {
    return __uint_as_float(((unsigned)u) << 16);
}
__device__ __forceinline__ u16 f2bf(float f) {
    unsigned u = __float_as_uint(f);
    unsigned r = (u + 0x7FFFu + ((u >> 16) & 1u)) >> 16;
    return (u16)r;
}

// ---------- prep kernels ----------
// in [count][R][C] f32 -> out [count][C][R]
__global__ void transpose_f32(const float* __restrict__ in, float* __restrict__ out,
                              int R, int C, long total) {
    long i = (long)blockIdx.x * 256 + threadIdx.x;
    if (i >= total) return;
    long rc = (long)R * C;
    long mat = i / rc;
    long rem = i - mat * rc;
    int c = (int)(rem / R);
    int r = (int)(rem - (long)c * R);
    out[i] = in[mat * rc + (long)r * C + c];
}

__global__ void transpose_bf16(const float* __restrict__ in, u16* __restrict__ out,
                               int R, int C, long total) {
    long i = (long)blockIdx.x * 256 + threadIdx.x;
    if (i >= total) return;
    long rc = (long)R * C;
    long mat = i / rc;
    long rem = i - mat * rc;
    int c = (int)(rem / R);
    int r = (int)(rem - (long)c * R);
    out[i] = f2bf(in[mat * rc + (long)r * C + c]);
}

__global__ void f32_to_bf16(const float* __restrict__ in, u16* __restrict__ out, long n) {
    long i = (long)blockIdx.x * 256 + threadIdx.x;
    if (i < n) out[i] = f2bf(in[i]);
}

// ---------- input GEMM: gi[d][m][g] = sum_k A[m][k] * wiT[d][k][g] + bias[d][g] ----------
// A bf16 [M=SB][K], wiT f32 [2][K][G3], out bf16 [2][SB][G3]
__global__ __launch_bounds__(256) void gemm_gi(
    const u16* __restrict__ A,
    const float* __restrict__ Bt,
    const float* __restrict__ bias,
    u16* __restrict__ Cg,
    int K)
{
    const int M = SB;
    int d = blockIdx.z;
    const float* Bm = Bt + (size_t)d * K * G3;
    const float* bi = bias + d * G3;
    u16* Cm = Cg + (size_t)d * M * G3;

    __shared__ float As[8][132];
    __shared__ float Bs[8][132];

    int n0 = blockIdx.x * 128;
    int m0 = blockIdx.y * 128;
    int tid = threadIdx.x;
    int tx = tid & 15, ty = tid >> 4;

    float acc[2][2][4][4] = {};

    for (int k0 = 0; k0 < K; k0 += 8) {
        if (tid < 128) {
            const u16* ap = A + (size_t)(m0 + tid) * K + k0;
            uint4 av = *reinterpret_cast<const uint4*>(ap); // 8 bf16
            const u16* pu = reinterpret_cast<const u16*>(&av);
#pragma unroll
            for (int kk = 0; kk < 8; kk++) As[kk][tid] = bf2f(pu[kk]);
        } else {
            int t = tid - 128;
            int kr = t >> 4;
            int c8 = (t & 15) * 8;
            const float* bp = Bm + (size_t)(k0 + kr) * G3 + n0 + c8;
            float4 v0 = *reinterpret_cast<const float4*>(bp);
            float4 v1 = *reinterpret_cast<const float4*>(bp + 4);
            *reinterpret_cast<float4*>(&Bs[kr][c8]) = v0;
            *reinterpret_cast<float4*>(&Bs[kr][c8 + 4]) = v1;
        }
        __syncthreads();
#pragma unroll
        for (int kk = 0; kk < 8; kk++) {
            float a0[4], a1[4], b0[4], b1[4];
            *reinterpret_cast<float4*>(a0) = *reinterpret_cast<const float4*>(&As[kk][ty * 4]);
            *reinterpret_cast<float4*>(a1) = *reinterpret_cast<const float4*>(&As[kk][64 + ty * 4]);
            *reinterpret_cast<float4*>(b0) = *reinterpret_cast<const float4*>(&Bs[kk][tx * 4]);
            *reinterpret_cast<float4*>(b1) = *reinterpret_cast<const float4*>(&Bs[kk][64 + tx * 4]);
#pragma unroll
            for (int i = 0; i < 4; i++) {
#pragma unroll
                for (int j = 0; j < 4; j++) {
                    acc[0][0][i][j] += a0[i] * b0[j];
                    acc[0][1][i][j] += a0[i] * b1[j];
                    acc[1][0][i][j] += a1[i] * b0[j];
                    acc[1][1][i][j] += a1[i] * b1[j];
                }
            }
        }
        __syncthreads();
    }
#pragma unroll
    for (int mb = 0; mb < 2; mb++) {
#pragma unroll
        for (int i = 0; i < 4; i++) {
            int m = m0 + mb * 64 + ty * 4 + i;
#pragma unroll
            for (int nb = 0; nb < 2; nb++) {
#pragma unroll
                for (int j = 0; j < 4; j++) {
                    int n = n0 + nb * 64 + tx * 4 + j;
                    Cm[(size_t)m * G3 + n] = f2bf(acc[mb][nb][i][j] + bi[n]);
                }
            }
        }
    }
}

// ---------- recurrent scan: one block per (batch row, direction) ----------
__global__ __launch_bounds__(768) void gru_scan(
    const u16* __restrict__ whhT,   // [12][256][768] bf16
    const float* __restrict__ bhh,  // [6][2][768]
    const u16* __restrict__ gi,     // [2][SB][768] bf16
    const float* __restrict__ h0,   // [12][64][256]
    u16* __restrict__ outc,         // [SB][512] bf16 or nullptr
    float* __restrict__ finals,     // [12][64][256]
    int layer)
{
    int b = blockIdx.x;
    int d = blockIdx.y;
    int tid = threadIdx.x;

    int ld = layer * 2 + d;
    const u16* W = whhT + (size_t)ld * HID * G3;
    const float* bh = bhh + (size_t)ld * G3;
    const u16* gid = gi + (size_t)d * SB * G3;

    __shared__ float h_s[HID];
    __shared__ float gh_s[G3];

    if (tid < HID) h_s[tid] = h0[(size_t)ld * BATCH * HID + b * HID + tid];
    __syncthreads();

    float bias_g = bh[tid];
    const u16* wcol = W + tid;

    for (int t = 0; t < S_LEN; t++) {
        int s = d ? (S_LEN - 1 - t) : t;
        // phase 1: gh[g] = bias + sum_k h[k]*W[k][g]
        float acc = bias_g;
        const u16* wp = wcol;
#pragma unroll 4
        for (int k = 0; k < HID; k += 4) {
            float4 hv = *reinterpret_cast<const float4*>(&h_s[k]);
            float w0 = bf2f(wp[0]);
            float w1 = bf2f(wp[G3]);
            float w2 = bf2f(wp[2 * G3]);
            float w3 = bf2f(wp[3 * G3]);
            wp += 4 * G3;
            acc += hv.x * w0;
            acc += hv.y * w1;
            acc += hv.z * w2;
            acc += hv.w * w3;
        }
        gh_s[tid] = acc;
        __syncthreads();
        // phase 2
        if (tid < HID) {
            int j = tid;
            size_t gbase = ((size_t)s * BATCH + b) * G3;
            float gir = bf2f(gid[gbase + j]);
            float giz = bf2f(gid[gbase + HID + j]);
            float gin = bf2f(gid[gbase + 2 * HID + j]);
            float r = 1.f / (1.f + __expf(-(gir + gh_s[j])));
            float z = 1.f / (1.f + __expf(-(giz + gh_s[HID + j])));
            float n = tanhf(gin + r * gh_s[2 * HID + j]);
            float hn = (1.f - z) * n + z * h_s[j];
            h_s[j] = hn;
            if (outc) outc[((size_t)s * BATCH + b) * D2 + d * HID + j] = f2bf(hn);
        }
        __syncthreads();
    }
    if (tid < HID)
        finals[(size_t)ld * BATCH * HID + b * HID + tid] = h_s[tid];
}

extern "C" void kernel_launch(void* const* d_in, const int* in_sizes, int n_in,
                              void* d_out, int out_size, void* d_ws, size_t ws_size,
                              hipStream_t stream) {
    const float* x     = (const float*)d_in[0];
    const float* h0    = (const float*)d_in[1];
    const float* w_ih0 = (const float*)d_in[2];
    const float* b_ih0 = (const float*)d_in[3];
    const float* w_ih  = (const float*)d_in[4];
    const float* b_ih  = (const float*)d_in[5];
    const float* w_hh  = (const float*)d_in[6];
    const float* b_hh  = (const float*)d_in[7];
    float* out = (float*)d_out;

    char* ws = (char*)d_ws;
    // layout (bytes):
    // whhT bf16 [12][256][768]          @ 0          size 4,718,592
    // wiT0 f32  [2][128][768]           @ 4718592    size 786,432
    // wiTl f32  [10][512][768]          @ 5505024    size 15,728,640
    // gi   bf16 [2][SB][768]            @ 21233664   size 100,663,296
    // curA bf16 [SB][512]               @ 121896960  size 33,554,432
    // curB bf16 [SB][512]               @ 155451392  size 33,554,432
    u16*   whhT = (u16*)(ws + 0);
    float* wiT0 = (float*)(ws + 4718592);
    float* wiTl = (float*)(ws + 5505024);
    u16*   gi   = (u16*)(ws + 21233664);
    u16*   curA = (u16*)(ws + 121896960);
    u16*   curB = (u16*)(ws + 155451392);

    transpose_bf16<<<(2359296 + 255) / 256, 256, 0, stream>>>(w_hh, whhT, 768, 256, 2359296L);
    transpose_f32<<<(196608 + 255) / 256, 256, 0, stream>>>(w_ih0, wiT0, 768, 128, 196608L);
    transpose_f32<<<(3932160 + 255) / 256, 256, 0, stream>>>(w_ih, wiTl, 768, 512, 3932160L);
    f32_to_bf16<<<(4194304 + 255) / 256, 256, 0, stream>>>(x, curA, 4194304L);

    u16* cin = curA;
    u16* cout_ = curB;
    for (int l = 0; l < 6; l++) {
        int K = l ? 512 : 128;
        const float* wt = l ? (wiTl + (size_t)(l - 1) * 2 * 512 * 768) : wiT0;
        const float* bi = l ? (b_ih + (size_t)(l - 1) * 2 * 768) : b_ih0;
        dim3 g(6, 256, 2); // N/128, M/128, dirs
        gemm_gi<<<g, 256, 0, stream>>>(cin, wt, bi, gi, K);
        gru_scan<<<dim3(64, 2), 768, 0, stream>>>(whhT, b_hh, gi, h0,
                                                  (l < 5) ? cout_ : (u16*)nullptr, out, l);
        u16* tmp = cin; cin = cout_; cout_ = tmp;
    }
}

// Round 2
// 7376.422 us; speedup vs baseline: 3.2634x; 3.2634x over previous
//
#include <hip/hip_runtime.h>
#include <hip/hip_bf16.h>
#include <cstddef>

#define S_LEN 512
#define BATCH 64
#define HID 256
#define G3 768
#define SB (S_LEN*BATCH)
#define D2 512

typedef unsigned short u16;
typedef _Float16 h2v __attribute__((ext_vector_type(2)));

__device__ __forceinline__ float bf2f(u16 u) {
    return __uint_as_float(((unsigned)u) << 16);
}
__device__ __forceinline__ u16 f2bf(float f) {
    unsigned u = __float_as_uint(f);
    unsigned r = (u + 0x7FFFu + ((u >> 16) & 1u)) >> 16;
    return (u16)r;
}
__device__ __forceinline__ u16 f2h_bits(float f) {
    _Float16 h = (_Float16)f;
    union { _Float16 h; u16 u; } cv; cv.h = h;
    return cv.u;
}
__device__ __forceinline__ h2v u2h(unsigned u) {
    union { unsigned u; h2v h; } cv; cv.u = u;
    return cv.h;
}
__device__ __forceinline__ float dot2f(unsigned w, unsigned h, float acc) {
#if __has_builtin(__builtin_amdgcn_fdot2)
    return __builtin_amdgcn_fdot2(u2h(w), u2h(h), acc, false);
#else
    h2v wv = u2h(w), hv = u2h(h);
    return acc + (float)wv.x * (float)hv.x + (float)wv.y * (float)hv.y;
#endif
}

// ---------- prep kernels ----------
// in [count][R][C] f32 -> out [count][C][R]
__global__ void transpose_f32(const float* __restrict__ in, float* __restrict__ out,
                              int R, int C, long total) {
    long i = (long)blockIdx.x * 256 + threadIdx.x;
    if (i >= total) return;
    long rc = (long)R * C;
    long mat = i / rc;
    long rem = i - mat * rc;
    int c = (int)(rem / R);
    int r = (int)(rem - (long)c * R);
    out[i] = in[mat * rc + (long)r * C + c];
}

// w_hh f32 [12][768][256] -> packed half2 [12][128][768] u32:
// out[mat][k2][g] = half2(w[mat][g][2k2], w[mat][g][2k2+1])
__global__ void pack_whh_f16(const float* __restrict__ in, unsigned* __restrict__ out,
                             long total) {
    long i = (long)blockIdx.x * 256 + threadIdx.x;
    if (i >= total) return;
    long mat = i / (128L * G3);
    long rem = i - mat * (128L * G3);
    int k2 = (int)(rem / G3);
    int g  = (int)(rem - (long)k2 * G3);
    const float* base = in + mat * (768L * 256) + (long)g * 256 + 2 * k2;
    unsigned lo = f2h_bits(base[0]);
    unsigned hi = f2h_bits(base[1]);
    out[i] = lo | (hi << 16);
}

__global__ void f32_to_bf16(const float* __restrict__ in, u16* __restrict__ out, long n) {
    long i = (long)blockIdx.x * 256 + threadIdx.x;
    if (i < n) out[i] = f2bf(in[i]);
}

// ---------- input GEMM: gi[d][m][g] = sum_k A[m][k] * wiT[d][k][g] + bias[d][g] ----------
__global__ __launch_bounds__(256) void gemm_gi(
    const u16* __restrict__ A,
    const float* __restrict__ Bt,
    const float* __restrict__ bias,
    u16* __restrict__ Cg,
    int K)
{
    int d = blockIdx.z;
    const float* Bm = Bt + (size_t)d * K * G3;
    const float* bi = bias + d * G3;
    u16* Cm = Cg + (size_t)d * SB * G3;

    __shared__ float As[8][132];
    __shared__ float Bs[8][132];

    int n0 = blockIdx.x * 128;
    int m0 = blockIdx.y * 128;
    int tid = threadIdx.x;
    int tx = tid & 15, ty = tid >> 4;

    float acc[2][2][4][4] = {};

    for (int k0 = 0; k0 < K; k0 += 8) {
        if (tid < 128) {
            const u16* ap = A + (size_t)(m0 + tid) * K + k0;
            uint4 av = *reinterpret_cast<const uint4*>(ap);
            const u16* pu = reinterpret_cast<const u16*>(&av);
#pragma unroll
            for (int kk = 0; kk < 8; kk++) As[kk][tid] = bf2f(pu[kk]);
        } else {
            int t = tid - 128;
            int kr = t >> 4;
            int c8 = (t & 15) * 8;
            const float* bp = Bm + (size_t)(k0 + kr) * G3 + n0 + c8;
            float4 v0 = *reinterpret_cast<const float4*>(bp);
            float4 v1 = *reinterpret_cast<const float4*>(bp + 4);
            *reinterpret_cast<float4*>(&Bs[kr][c8]) = v0;
            *reinterpret_cast<float4*>(&Bs[kr][c8 + 4]) = v1;
        }
        __syncthreads();
#pragma unroll
        for (int kk = 0; kk < 8; kk++) {
            float a0[4], a1[4], b0[4], b1[4];
            *reinterpret_cast<float4*>(a0) = *reinterpret_cast<const float4*>(&As[kk][ty * 4]);
            *reinterpret_cast<float4*>(a1) = *reinterpret_cast<const float4*>(&As[kk][64 + ty * 4]);
            *reinterpret_cast<float4*>(b0) = *reinterpret_cast<const float4*>(&Bs[kk][tx * 4]);
            *reinterpret_cast<float4*>(b1) = *reinterpret_cast<const float4*>(&Bs[kk][64 + tx * 4]);
#pragma unroll
            for (int i = 0; i < 4; i++) {
#pragma unroll
                for (int j = 0; j < 4; j++) {
                    acc[0][0][i][j] += a0[i] * b0[j];
                    acc[0][1][i][j] += a0[i] * b1[j];
                    acc[1][0][i][j] += a1[i] * b0[j];
                    acc[1][1][i][j] += a1[i] * b1[j];
                }
            }
        }
        __syncthreads();
    }
#pragma unroll
    for (int mb = 0; mb < 2; mb++) {
#pragma unroll
        for (int i = 0; i < 4; i++) {
            int m = m0 + mb * 64 + ty * 4 + i;
#pragma unroll
            for (int nb = 0; nb < 2; nb++) {
#pragma unroll
                for (int j = 0; j < 4; j++) {
                    int n = n0 + nb * 64 + tx * 4 + j;
                    Cm[(size_t)m * G3 + n] = f2bf(acc[mb][nb][i][j] + bi[n]);
                }
            }
        }
    }
}

// ---------- recurrent scan: one block per (batch row, direction) ----------
// W_hh^T register-resident as packed f16 pairs; h f32 in per-thread register,
// f16 mirror in LDS for the dot phase.
__global__ __launch_bounds__(768, 3) void gru_scan(
    const unsigned* __restrict__ wpack,  // [12][128][768] u32 (half2 pairs over k)
    const float* __restrict__ bhh,       // [6][2][768]
    const u16* __restrict__ gi,          // [2][SB][768] bf16
    const float* __restrict__ h0,        // [12][64][256]
    u16* __restrict__ outc,              // [SB][512] bf16 or nullptr
    float* __restrict__ finals,          // [12][64][256]
    int layer)
{
    int b = blockIdx.x;
    int d = blockIdx.y;
    int tid = threadIdx.x;

    int ld = layer * 2 + d;
    const unsigned* Wp = wpack + (size_t)ld * 128 * G3 + tid;
    const u16* gid = gi + (size_t)d * SB * G3;

    __shared__ float gh_s[G3];
    __shared__ alignas(16) _Float16 h16_s[HID];

    // load weight column into registers (coalesced: consecutive tid -> consecutive u32)
    unsigned wpk[128];
#pragma unroll
    for (int k = 0; k < 128; k++) wpk[k] = Wp[(size_t)k * G3];

    float bias_g = bhh[(size_t)ld * G3 + tid];

    float hreg = 0.f;
    if (tid < HID) {
        hreg = h0[(size_t)ld * BATCH * HID + b * HID + tid];
        h16_s[tid] = (_Float16)hreg;
    }
    __syncthreads();

    for (int t = 0; t < S_LEN; t++) {
        int s = d ? (S_LEN - 1 - t) : t;
        // phase 1: gh[g] = bias + sum_k h[k]*W[k][g]  (f16 dot2, f32 accum)
        float acc = bias_g;
        const uint4* hp = reinterpret_cast<const uint4*>(h16_s);
#pragma unroll
        for (int k = 0; k < 32; k++) {
            uint4 q = hp[k];
            acc = dot2f(wpk[4 * k + 0], q.x, acc);
            acc = dot2f(wpk[4 * k + 1], q.y, acc);
            acc = dot2f(wpk[4 * k + 2], q.z, acc);
            acc = dot2f(wpk[4 * k + 3], q.w, acc);
        }
        gh_s[tid] = acc;
        __syncthreads();
        // phase 2: gates + state update (threads 0..255)
        if (tid < HID) {
            int j = tid;
            size_t gbase = ((size_t)s * BATCH + b) * G3;
            float gir = bf2f(gid[gbase + j]);
            float giz = bf2f(gid[gbase + HID + j]);
            float gin = bf2f(gid[gbase + 2 * HID + j]);
            float r = 1.f / (1.f + __expf(-(gir + gh_s[j])));
            float z = 1.f / (1.f + __expf(-(giz + gh_s[HID + j])));
            float n = tanhf(gin + r * gh_s[2 * HID + j]);
            float hn = (1.f - z) * n + z * hreg;
            hreg = hn;
            h16_s[j] = (_Float16)hn;
            if (outc) outc[((size_t)s * BATCH + b) * D2 + d * HID + j] = f2bf(hn);
        }
        __syncthreads();
    }
    if (tid < HID)
        finals[(size_t)ld * BATCH * HID + b * HID + tid] = hreg;
}

extern "C" void kernel_launch(void* const* d_in, const int* in_sizes, int n_in,
                              void* d_out, int out_size, void* d_ws, size_t ws_size,
                              hipStream_t stream) {
    const float* x     = (const float*)d_in[0];
    const float* h0    = (const float*)d_in[1];
    const float* w_ih0 = (const float*)d_in[2];
    const float* b_ih0 = (const float*)d_in[3];
    const float* w_ih  = (const float*)d_in[4];
    const float* b_ih  = (const float*)d_in[5];
    const float* w_hh  = (const float*)d_in[6];
    const float* b_hh  = (const float*)d_in[7];
    float* out = (float*)d_out;

    char* ws = (char*)d_ws;
    // layout (bytes):
    // wpack u32 [12][128][768]          @ 0          size 4,718,592
    // wiT0 f32  [2][128][768]           @ 4718592    size 786,432
    // wiTl f32  [10][512][768]          @ 5505024    size 15,728,640
    // gi   bf16 [2][SB][768]            @ 21233664   size 100,663,296
    // curA bf16 [SB][512]               @ 121896960  size 33,554,432
    // curB bf16 [SB][512]               @ 155451392  size 33,554,432
    unsigned* wpack = (unsigned*)(ws + 0);
    float* wiT0 = (float*)(ws + 4718592);
    float* wiTl = (float*)(ws + 5505024);
    u16*   gi   = (u16*)(ws + 21233664);
    u16*   curA = (u16*)(ws + 121896960);
    u16*   curB = (u16*)(ws + 155451392);

    pack_whh_f16<<<(1179648 + 255) / 256, 256, 0, stream>>>(w_hh, wpack, 1179648L);
    transpose_f32<<<(196608 + 255) / 256, 256, 0, stream>>>(w_ih0, wiT0, 768, 128, 196608L);
    transpose_f32<<<(3932160 + 255) / 256, 256, 0, stream>>>(w_ih, wiTl, 768, 512, 3932160L);
    f32_to_bf16<<<(4194304 + 255) / 256, 256, 0, stream>>>(x, curA, 4194304L);

    u16* cin = curA;
    u16* cout_ = curB;
    for (int l = 0; l < 6; l++) {
        int K = l ? 512 : 128;
        const float* wt = l ? (wiTl + (size_t)(l - 1) * 2 * 512 * 768) : wiT0;
        const float* bi = l ? (b_ih + (size_t)(l - 1) * 2 * 768) : b_ih0;
        dim3 g(6, 256, 2); // N/128, M/128, dirs
        gemm_gi<<<g, 256, 0, stream>>>(cin, wt, bi, gi, K);
        gru_scan<<<dim3(64, 2), 768, 0, stream>>>(wpack, b_hh, gi, h0,
                                                  (l < 5) ? cout_ : (u16*)nullptr, out, l);
        u16* tmp = cin; cin = cout_; cout_ = tmp;
    }
}

// Round 3
// 4066.494 us; speedup vs baseline: 5.9196x; 1.8140x over previous
//
#include <hip/hip_runtime.h>
#include <hip/hip_bf16.h>
#include <cstddef>

#define S_LEN 512
#define BATCH 64
#define HID 256
#define G3 768
#define SB (S_LEN*BATCH)
#define D2 512

typedef unsigned short u16;
typedef _Float16 h2v __attribute__((ext_vector_type(2)));
typedef __attribute__((ext_vector_type(8))) short s16x8;
typedef __attribute__((ext_vector_type(4))) float f32x4;

__device__ __forceinline__ float bf2f(u16 u) {
    return __uint_as_float(((unsigned)u) << 16);
}
__device__ __forceinline__ u16 f2bf(float f) {
    unsigned u = __float_as_uint(f);
    unsigned r = (u + 0x7FFFu + ((u >> 16) & 1u)) >> 16;
    return (u16)r;
}
__device__ __forceinline__ u16 f2h_bits(float f) {
    _Float16 h = (_Float16)f;
    union { _Float16 h; u16 u; } cv; cv.h = h;
    return cv.u;
}
__device__ __forceinline__ h2v u2h(unsigned u) {
    union { unsigned u; h2v h; } cv; cv.u = u;
    return cv.h;
}
__device__ __forceinline__ float dot2f(unsigned w, unsigned h, float acc) {
#if __has_builtin(__builtin_amdgcn_fdot2)
    return __builtin_amdgcn_fdot2(u2h(w), u2h(h), acc, false);
#else
    h2v wv = u2h(w), hv = u2h(h);
    return acc + (float)wv.x * (float)hv.x + (float)wv.y * (float)hv.y;
#endif
}
__device__ __forceinline__ float fast_rcp(float x) {
#if __has_builtin(__builtin_amdgcn_rcpf)
    return __builtin_amdgcn_rcpf(x);
#else
    return 1.f / x;
#endif
}
__device__ __forceinline__ void gload_lds16(const void* g, void* l) {
    __builtin_amdgcn_global_load_lds((const __attribute__((address_space(1))) void*)g,
                                     (__attribute__((address_space(3))) void*)l, 16, 0, 0);
}

// ---------- prep kernels ----------
// w_hh f32 [12][768][256] -> packed half2 [12][128][768] u32:
// out[mat][k2][g] = half2(w[mat][g][2k2], w[mat][g][2k2+1])
__global__ void pack_whh_f16(const float* __restrict__ in, unsigned* __restrict__ out,
                             long total) {
    long i = (long)blockIdx.x * 256 + threadIdx.x;
    if (i >= total) return;
    long mat = i / (128L * G3);
    long rem = i - mat * (128L * G3);
    int k2 = (int)(rem / G3);
    int g  = (int)(rem - (long)k2 * G3);
    const float* base = in + mat * (768L * 256) + (long)g * 256 + 2 * k2;
    unsigned lo = f2h_bits(base[0]);
    unsigned hi = f2h_bits(base[1]);
    out[i] = lo | (hi << 16);
}

__global__ void f32_to_bf16(const float* __restrict__ in, u16* __restrict__ out, long n) {
    long i = (long)blockIdx.x * 256 + threadIdx.x;
    if (i < n) out[i] = f2bf(in[i]);
}

// ---------- input GEMM (MFMA): gi[d][m][g] = sum_k A[m][k]*W[d][g][k] + bias[d][g] ----------
// A bf16 [SB][K] row-major; Bt bf16 [2][768][K] (= B^T, native w_ih layout); out bf16 [2][SB][768]
__global__ __launch_bounds__(256, 2) void gemm_mfma(
    const u16* __restrict__ A,
    const u16* __restrict__ Bt,
    const float* __restrict__ bias,   // [2][768]
    u16* __restrict__ Cg,
    int K)
{
    int d = blockIdx.z;
    const u16* Bb = Bt + (size_t)d * 768 * K;
    const float* bi = bias + d * G3;
    u16* Cm = Cg + (size_t)d * SB * G3;

    int n0 = blockIdx.x * 128;
    int m0 = blockIdx.y * 128;
    int tid = threadIdx.x;
    int wave = tid >> 6, lane = tid & 63;
    int wm = wave >> 1, wn = wave & 1;

    __shared__ u16 Asm[128 * 32];  // [row][k] 64B rows
    __shared__ u16 Bsm[128 * 32];

    f32x4 acc[4][4] = {};

    for (int k0 = 0; k0 < K; k0 += 32) {
#pragma unroll
        for (int p = 0; p < 2; p++) {
            int c = p * 256 + wave * 64 + lane;      // chunk: 512 chunks of 16B per tile
            int row = c >> 2, kc = c & 3;
            const u16* srcA = A + (size_t)(m0 + row) * K + k0 + kc * 8;
            const u16* srcB = Bb + (size_t)(n0 + row) * K + k0 + kc * 8;
            // LDS dest: wave-uniform base; HW adds lane*16
            gload_lds16(srcA, &Asm[(p * 256 + wave * 64) * 8]);
            gload_lds16(srcB, &Bsm[(p * 256 + wave * 64) * 8]);
        }
        __syncthreads();

        s16x8 af[4], bfr[4];
#pragma unroll
        for (int i = 0; i < 4; i++) {
            int arow = wm * 64 + i * 16 + (lane & 15);
            af[i] = *reinterpret_cast<const s16x8*>(&Asm[arow * 32 + (lane >> 4) * 8]);
            int brow = wn * 64 + i * 16 + (lane & 15);
            bfr[i] = *reinterpret_cast<const s16x8*>(&Bsm[brow * 32 + (lane >> 4) * 8]);
        }
#pragma unroll
        for (int i = 0; i < 4; i++)
#pragma unroll
            for (int j = 0; j < 4; j++)
                acc[i][j] = __builtin_amdgcn_mfma_f32_16x16x32_bf16(af[i], bfr[j], acc[i][j], 0, 0, 0);
        __syncthreads();
    }

    int lcol = lane & 15, lrow4 = (lane >> 4) * 4;
#pragma unroll
    for (int i = 0; i < 4; i++) {
#pragma unroll
        for (int j = 0; j < 4; j++) {
            int n = n0 + wn * 64 + j * 16 + lcol;
            float bv = bi[n];
#pragma unroll
            for (int q = 0; q < 4; q++) {
                int m = m0 + wm * 64 + i * 16 + lrow4 + q;
                Cm[(size_t)m * G3 + n] = f2bf(acc[i][j][q] + bv);
            }
        }
    }
}

// ---------- recurrent scan ----------
// Register-resident W_hh^T (f16 pairs); gi[t+1] prefetched into LDS during the dot.
__global__ __launch_bounds__(768, 3) void gru_scan(
    const unsigned* __restrict__ wpack,  // [12][128][768] u32 (half2 pairs over k)
    const float* __restrict__ bhh,       // [6][2][768]
    const u16* __restrict__ gi,          // [2][SB][768] bf16
    const float* __restrict__ h0,        // [12][64][256]
    u16* __restrict__ outc,              // [SB][512] bf16 or nullptr
    float* __restrict__ finals,          // [12][64][256]
    int layer)
{
    int b = blockIdx.x;
    int d = blockIdx.y;
    int tid = threadIdx.x;

    int ld = layer * 2 + d;
    const unsigned* Wp = wpack + (size_t)ld * 128 * G3 + tid;
    const u16* gid = gi + (size_t)d * SB * G3;

    __shared__ float gh_s[G3];
    __shared__ alignas(16) _Float16 h16_s[HID];
    __shared__ u16 gi_s[2][G3];

    unsigned wpk[128];
#pragma unroll
    for (int k = 0; k < 128; k++) wpk[k] = Wp[(size_t)k * G3];

    float bias_g = bhh[(size_t)ld * G3 + tid];

    float hreg = 0.f;
    if (tid < HID) {
        hreg = h0[(size_t)ld * BATCH * HID + b * HID + tid];
        h16_s[tid] = (_Float16)hreg;
    }
    // prefetch step 0's gi
    {
        int s0 = d ? (S_LEN - 1) : 0;
        gi_s[0][tid] = gid[((size_t)s0 * BATCH + b) * G3 + tid];
    }
    __syncthreads();

    for (int t = 0; t < S_LEN; t++) {
        int s = d ? (S_LEN - 1 - t) : t;
        // issue next step's gi load early; lands in LDS before the barrier
        u16 ginext = 0;
        if (t + 1 < S_LEN) {
            int sn = d ? (s - 1) : (s + 1);
            ginext = gid[((size_t)sn * BATCH + b) * G3 + tid];
        }
        // phase 1: gh[g] = bias + sum_k h[k]*W[k][g]  (f16 dot2, f32 accum)
        float acc = bias_g;
        const uint4* hp = reinterpret_cast<const uint4*>(h16_s);
#pragma unroll
        for (int k = 0; k < 32; k++) {
            uint4 q = hp[k];
            acc = dot2f(wpk[4 * k + 0], q.x, acc);
            acc = dot2f(wpk[4 * k + 1], q.y, acc);
            acc = dot2f(wpk[4 * k + 2], q.z, acc);
            acc = dot2f(wpk[4 * k + 3], q.w, acc);
        }
        gh_s[tid] = acc;
        gi_s[(t + 1) & 1][tid] = ginext;
        __syncthreads();
        // phase 2: gates + state update (threads 0..255), gi from LDS
        if (tid < HID) {
            int j = tid;
            const u16* gs = gi_s[t & 1];
            float gir = bf2f(gs[j]);
            float giz = bf2f(gs[HID + j]);
            float gin = bf2f(gs[2 * HID + j]);
            float r = fast_rcp(1.f + __expf(-(gir + gh_s[j])));
            float z = fast_rcp(1.f + __expf(-(giz + gh_s[HID + j])));
            float xn = gin + r * gh_s[2 * HID + j];
            float e2 = __expf(2.f * xn);
            float n = 1.f - 2.f * fast_rcp(e2 + 1.f);
            float hn = (1.f - z) * n + z * hreg;
            hreg = hn;
            h16_s[j] = (_Float16)hn;
            if (outc) outc[((size_t)s * BATCH + b) * D2 + d * HID + j] = f2bf(hn);
        }
        __syncthreads();
    }
    if (tid < HID)
        finals[(size_t)ld * BATCH * HID + b * HID + tid] = hreg;
}

extern "C" void kernel_launch(void* const* d_in, const int* in_sizes, int n_in,
                              void* d_out, int out_size, void* d_ws, size_t ws_size,
                              hipStream_t stream) {
    const float* x     = (const float*)d_in[0];
    const float* h0    = (const float*)d_in[1];
    const float* w_ih0 = (const float*)d_in[2];
    const float* b_ih0 = (const float*)d_in[3];
    const float* w_ih  = (const float*)d_in[4];
    const float* b_ih  = (const float*)d_in[5];
    const float* w_hh  = (const float*)d_in[6];
    const float* b_hh  = (const float*)d_in[7];
    float* out = (float*)d_out;

    char* ws = (char*)d_ws;
    // layout (bytes):
    // wpack u32 [12][128][768]    @ 0           size 4,718,592
    // wbf0  bf16 [2][768][128]    @ 4,718,592   size 393,216
    // wbfl  bf16 [5][2][768][512] @ 5,111,808   size 7,864,320
    // gi    bf16 [2][SB][768]     @ 12,976,128  size 100,663,296
    // curA  bf16 [SB][512]        @ 113,639,424 size 33,554,432
    // curB  bf16 [SB][512]        @ 147,193,856 size 33,554,432
    unsigned* wpack = (unsigned*)(ws + 0);
    u16* wbf0 = (u16*)(ws + 4718592);
    u16* wbfl = (u16*)(ws + 5111808);
    u16* gi   = (u16*)(ws + 12976128);
    u16* curA = (u16*)(ws + 113639424);
    u16* curB = (u16*)(ws + 147193856);

    pack_whh_f16<<<(1179648 + 255) / 256, 256, 0, stream>>>(w_hh, wpack, 1179648L);
    f32_to_bf16<<<(196608 + 255) / 256, 256, 0, stream>>>(w_ih0, wbf0, 196608L);
    f32_to_bf16<<<(3932160 + 255) / 256, 256, 0, stream>>>(w_ih, wbfl, 3932160L);
    f32_to_bf16<<<(4194304 + 255) / 256, 256, 0, stream>>>(x, curA, 4194304L);

    u16* cin = curA;
    u16* cout_ = curB;
    for (int l = 0; l < 6; l++) {
        int K = l ? 512 : 128;
        const u16* wt = l ? (wbfl + (size_t)(l - 1) * 2 * 768 * 512) : wbf0;
        const float* bi = l ? (b_ih + (size_t)(l - 1) * 2 * 768) : b_ih0;
        dim3 g(6, 256, 2); // N/128, M/128, dirs
        gemm_mfma<<<g, 256, 0, stream>>>(cin, wt, bi, gi, K);
        gru_scan<<<dim3(64, 2), 768, 0, stream>>>(wpack, b_hh, gi, h0,
                                                  (l < 5) ? cout_ : (u16*)nullptr, out, l);
        u16* tmp = cin; cin = cout_; cout_ = tmp;
    }
}